// Round 12
// baseline (10379.233 us; speedup 1.0000x reference)
//
#include <hip/hip_runtime.h>
#include <math.h>

// ---------------------------------------------------------------------------
// 2-layer LSTM, B=64 T=512 I=256 H=768, fp32 in/out.
// Round 12: barrier-free persistent kernel. Each wave = independent pipeline
// (16 batches x 4 units, full-K): no pre[] exchange, NO __syncthreads in the
// step loop. Batch-groups (m) are independent pipelines (LSTM never mixes
// batches). Gate transpose in-wave via private LDS scratch (lockstep +
// lgkmcnt). Sync = r10's proven discipline: per-wave flags posted after own
// vmcnt(0) ack; consumers do ONE batched flag wait then ONE batched data
// burst (r11 lesson: never interleave poll/load per chunk).
// Weights in LDS. fp16 MFMA 16x16x32, fragment-major operands.
// ---------------------------------------------------------------------------

#define B_   64
#define T_   512
#define I_   256
#define H_   768
#define G4H  3072

constexpr size_t BTH = (size_t)B_ * T_ * H_;   // 25165824
constexpr size_t BH  = (size_t)B_ * H_;        // 49152

using f16_t = _Float16;
using f16x8 = __attribute__((ext_vector_type(8))) _Float16;
using f32x4 = __attribute__((ext_vector_type(4))) float;
typedef unsigned long long u64;

#define MFMA(a, b, c) __builtin_amdgcn_mfma_f32_16x16x32_f16((a), (b), (c), 0, 0, 0)

// Ring: quantum u64 = 4 f16 units. addr = slot*98304 + ws*1024 + q*512 + b*8.
#define SLOT_STRIDE 98304        // 96*64*16 bytes
#define RING_SLOTS  16
#define RING_BYTES  (RING_SLOTS * SLOT_STRIDE)

// Per-wave flags: u64 entry per (t, m, ws) at 16B stride; halves = p0/p1.
// entry index = (t*4 + m)*96 + ws; u64 offset = index*2.
constexpr size_t WF_U64S  = (size_t)T_ * 4 * 96 * 2;   // 3 MB per layer
constexpr size_t WF_BYTES = WF_U64S * 8;

// LDS: WL[2][48][512] f16 (98304 B) | scr float[8][16][20] (10240 B) | bsL 128
#define SMEM_BYTES 108672

// ---------------------------------------------------------------------------
__global__ void k_packW(const float* __restrict__ src, f16_t* __restrict__ dst,
                        int K, int KC, int total) {
  int i = blockIdx.x * blockDim.x + threadIdx.x;
  int stride = gridDim.x * blockDim.x;
  for (; i < total; i += stride) {
    int e = i & 7;
    int lane = (i >> 3) & 63;
    int rest = i >> 9;          // ptile*KC + kc
    int kc = rest % KC;
    int ptile = rest / KC;
    int p = ptile * 16 + (lane & 15);
    int k = kc * 32 + (lane >> 4) * 8 + e;
    int r = (p & 3) * H_ + (p >> 2);
    dst[i] = (f16_t)src[(size_t)r * K + k];
  }
}

__global__ void k_packX(const float* __restrict__ x, f16_t* __restrict__ dst) {
  int i = blockIdx.x * blockDim.x + threadIdx.x;
  int stride = gridDim.x * blockDim.x;
  const int total = 4 * T_ * 8 * 64 * 8;  // 8,388,608
  for (; i < total; i += stride) {
    int e = i & 7;
    int lane = (i >> 3) & 63;
    int kc = (i >> 9) & 7;
    int t = (i >> 12) & 511;
    int mtile = i >> 21;
    int b = mtile * 16 + (lane & 15);
    int k = kc * 32 + (lane >> 4) * 8 + e;
    dst[i] = (f16_t)x[((size_t)b * T_ + t) * I_ + k];
  }
}

__global__ void k_bias(const float* __restrict__ bih, const float* __restrict__ bhh,
                       float* __restrict__ bsum) {
  int p = blockIdx.x * blockDim.x + threadIdx.x;
  if (p < G4H) {
    int r = (p & 3) * H_ + (p >> 2);
    bsum[p] = bih[r] + bhh[r];
  }
}

__global__ void k_zero(int4* __restrict__ d, int n) {
  int i = blockIdx.x * blockDim.x + threadIdx.x;
  if (i < n) d[i] = make_int4(0, 0, 0, 0);
}

__device__ __forceinline__ float sigf(float v) {
  return __builtin_amdgcn_rcpf(1.0f + __builtin_amdgcn_exp2f(v * -1.44269504f));
}
__device__ __forceinline__ float tanhf_fast(float v) {
  return 2.0f * __builtin_amdgcn_rcpf(1.0f + __builtin_amdgcn_exp2f(v * -2.88539008f)) - 1.0f;
}

__device__ __forceinline__ u64 ld_q(const u64* p) {
  return __hip_atomic_load(p, __ATOMIC_RELAXED, __HIP_MEMORY_SCOPE_AGENT);
}

// Batched flag wait: lane polls its 24 producer entries (ws' = kc*4 + l4),
// ALL in one round, then __all. 16B entry stride -> 1 line per entry-pair.
__device__ __forceinline__ void wait24(const u64* base, int l4, unsigned tagv) {
  const u64 exp = (u64)tagv * 0x100000001ULL;
  for (;;) {
    int ok = 1;
#pragma unroll
    for (int kc = 0; kc < 24; ++kc)
      ok &= (int)(ld_q(base + (size_t)(kc * 4 + l4) * 2) == exp);
    if (__all(ok)) return;
    __builtin_amdgcn_s_sleep(1);
  }
}

// ---------------------------------------------------------------------------
// Per-wave independent pipeline. Wave (m = wave>>1, p = wave&1) of WG ws:
// output = batches m*16..+16 x units ws*8+4p..+4, full K.
// L0: x-GEMM (8 chunks, no deps) + h0[t-1] (24 chunks).
// L1: h0[t] (24) + h1[t-1] (24); loads h1 first to overlap the h0 wait.
template <int KC, bool IS_L1>
__device__ __forceinline__ void run_layer(
    int ws, const f16_t* __restrict__ Xf, const f16_t* __restrict__ Wihf,
    const f16_t* __restrict__ Whhf, const float* __restrict__ bsum,
    char* __restrict__ ring0c, char* __restrict__ ring1c,
    u64* __restrict__ wf0, u64* __restrict__ wf1,
    float* __restrict__ out, char* smem) {
  f16_t* WL = (f16_t*)smem;                              // [2 p][KC][512]
  float (*scr)[16][20] = (float (*)[16][20])(smem + 98304);  // [wave][col][row20]
  float* bsL = (float*)(smem + 98304 + 10240);           // [32]

  const int tid = threadIdx.x;
  const int wave = tid >> 6, lane = tid & 63;
  const int m = wave >> 1, p = wave & 1;
  const int l15 = lane & 15, l4 = lane >> 4;
  const int laneo = lane * 8;

  if (tid < 32) bsL[tid] = bsum[ws * 32 + tid];

  // ---- stage W into LDS: wave stages chunks [m*CH, m*CH+CH) of phalf p ----
  {
    const int CH = KC / 4;
    const int ptile = ws * 2 + p;
    for (int c = m * CH; c < m * CH + CH; ++c) {
      const f16_t* src;
      if constexpr (!IS_L1)
        src = (c < 8) ? Wihf + ((size_t)ptile * 8 + c) * 512
                      : Whhf + ((size_t)ptile * 24 + (c - 8)) * 512;
      else
        src = (c < 24) ? Wihf + ((size_t)ptile * 24 + c) * 512
                       : Whhf + ((size_t)ptile * 24 + (c - 24)) * 512;
      *(uint4*)(WL + ((size_t)p * KC + c) * 512 + laneo) = *(const uint4*)(src + laneo);
    }
  }
  __syncthreads();   // only barrier in the kernel

  const f16_t* wl = WL + (size_t)p * KC * 512 + laneo;   // chunk i at wl + i*512
  const int bb = m * 16 + l15;        // this lane's batch (gate phase)
  const int j = ws * 8 + p * 4 + l4;  // this lane's unit  (gate phase)
  float c_reg = 0.f;
  char* myring = IS_L1 ? ring1c : ring0c;
  u64* mywf = IS_L1 ? wf1 : wf0;

  for (int t = 0; t < T_; ++t) {
    const int slot = t & (RING_SLOTS - 1);
    f32x4 accA = {0.f, 0.f, 0.f, 0.f};
    f32x4 accB = {0.f, 0.f, 0.f, 0.f};

    if constexpr (!IS_L1) {
      // ring guard (off critical path, 16-step slack): before overwriting
      // h0[t-16]'s rows for batch-group m, L1 waves (m) must be past t-16.
      if (t >= RING_SLOTS) {
        const u64* g = wf1 + (((size_t)(t - RING_SLOTS) * 4 + m) * 96) * 2;
        const u64 exp = (u64)(unsigned)(t - RING_SLOTS + 1) * 0x100000001ULL;
        for (;;) {
          u64 v0 = ld_q(g + lane * 2);
          u64 v1 = (lane < 32) ? ld_q(g + (64 + lane) * 2) : exp;
          if (__all((int)((v0 == exp) & (v1 == exp)))) break;
          __builtin_amdgcn_s_sleep(2);
        }
      }
      // x part (no recurrence dependency; runs while h0[t-1] settles)
      const f16_t* A0 = Xf + ((size_t)m * T_ + t) * 4096 + laneo;
#pragma unroll
      for (int i = 0; i < 8; ++i)
        accA = MFMA(*(const f16x8*)(A0 + (size_t)i * 512),
                    *(const f16x8*)(wl + (size_t)i * 512), accA);
      // h0[t-1]: ONE batched flag wait, then ONE batched data burst.
      if (t >= 1) {
        wait24(wf0 + (((size_t)(t - 1) * 4 + m) * 96) * 2, l4, (unsigned)t);
        const char* sb = ring0c + (size_t)((t - 1) & (RING_SLOTS - 1)) * SLOT_STRIDE;
        u64 lo[24], hi[24];
#pragma unroll
        for (int kc = 0; kc < 24; ++kc) {
          const u64* q = (const u64*)(sb + (size_t)(kc * 4 + l4) * 1024 + (size_t)bb * 8);
          lo[kc] = ld_q(q);
          hi[kc] = ld_q(q + 64);
        }
#pragma unroll
        for (int kc = 0; kc < 24; ++kc) {
          union { u64 q[2]; f16x8 f; } c;
          c.q[0] = lo[kc]; c.q[1] = hi[kc];
          f16x8 w = *(const f16x8*)(wl + (size_t)(8 + kc) * 512);
          if (kc & 1) accB = MFMA(c.f, w, accB);
          else        accA = MFMA(c.f, w, accA);
        }
      }
    } else {
      // h1[t-1] first (own layer, ready) -- its loads fly during the h0 wait.
      u64 lo1[24], hi1[24];
      if (t >= 1) {
        wait24(wf1 + (((size_t)(t - 1) * 4 + m) * 96) * 2, l4, (unsigned)t);
        const char* sb1 = ring1c + (size_t)((t - 1) & (RING_SLOTS - 1)) * SLOT_STRIDE;
#pragma unroll
        for (int kc = 0; kc < 24; ++kc) {
          const u64* q = (const u64*)(sb1 + (size_t)(kc * 4 + l4) * 1024 + (size_t)bb * 8);
          lo1[kc] = ld_q(q);
          hi1[kc] = ld_q(q + 64);
        }
      }
      // h0[t]: the real wait.
      wait24(wf0 + (((size_t)t * 4 + m) * 96) * 2, l4, (unsigned)(t + 1));
      const char* sb0 = ring0c + (size_t)(t & (RING_SLOTS - 1)) * SLOT_STRIDE;
      u64 lo0[24], hi0[24];
#pragma unroll
      for (int kc = 0; kc < 24; ++kc) {
        const u64* q = (const u64*)(sb0 + (size_t)(kc * 4 + l4) * 1024 + (size_t)bb * 8);
        lo0[kc] = ld_q(q);
        hi0[kc] = ld_q(q + 64);
      }
#pragma unroll
      for (int kc = 0; kc < 24; ++kc) {
        union { u64 q[2]; f16x8 f; } c;
        c.q[0] = lo0[kc]; c.q[1] = hi0[kc];
        f16x8 w = *(const f16x8*)(wl + (size_t)kc * 512);
        if (kc & 1) accB = MFMA(c.f, w, accB);
        else        accA = MFMA(c.f, w, accA);
      }
      if (t >= 1) {
#pragma unroll
        for (int kc = 0; kc < 24; ++kc) {
          union { u64 q[2]; f16x8 f; } c;
          c.q[0] = lo1[kc]; c.q[1] = hi1[kc];
          f16x8 w = *(const f16x8*)(wl + (size_t)(24 + kc) * 512);
          if (kc & 1) accB = MFMA(c.f, w, accB);
          else        accA = MFMA(c.f, w, accA);
        }
      }
    }

    f32x4 acc = accA + accB;

    // ---- in-wave transpose (C layout: col=lane&15, row=l4*4+r). Wave is
    // lockstep; lgkmcnt(0) + sched_barrier orders write->read. No barrier.
    *(f32x4*)&scr[wave][l15][l4 * 4] = acc;   // col l15, rows l4*4..+3
    asm volatile("s_waitcnt lgkmcnt(0)" ::: "memory");
    __builtin_amdgcn_sched_barrier(0);
    float g0 = scr[wave][4 * l4 + 0][l15] + bsL[p * 16 + 4 * l4 + 0];
    float g1 = scr[wave][4 * l4 + 1][l15] + bsL[p * 16 + 4 * l4 + 1];
    float g2 = scr[wave][4 * l4 + 2][l15] + bsL[p * 16 + 4 * l4 + 2];
    float g3 = scr[wave][4 * l4 + 3][l15] + bsL[p * 16 + 4 * l4 + 3];
    asm volatile("" ::: "memory");            // reads of t before writes of t+1

    float ig = sigf(g0), fg = sigf(g1), gg = tanhf_fast(g2), og = sigf(g3);
    c_reg = fg * c_reg + ig * gg;
    float h = og * tanhf_fast(c_reg);

    // ---- publish: lanes 0..15 gather units 0..3 of batch m*16+lane via shfl,
    // store one u64 quantum; own-wave vmcnt(0) ack; lane0 posts wave flag.
    unsigned hb = (unsigned)__builtin_bit_cast(unsigned short, (f16_t)h);
    unsigned q0 = (unsigned)__shfl((int)hb, l15 + 0);
    unsigned q1 = (unsigned)__shfl((int)hb, l15 + 16);
    unsigned q2 = (unsigned)__shfl((int)hb, l15 + 32);
    unsigned q3 = (unsigned)__shfl((int)hb, l15 + 48);
    if (lane < 16) {
      u64 val = (u64)(q0 | (q1 << 16)) | ((u64)(q2 | (q3 << 16)) << 32);
      u64* dst = (u64*)(myring + (size_t)slot * SLOT_STRIDE + (size_t)ws * 1024 +
                        (size_t)p * 512 + (size_t)(m * 16 + lane) * 8);
      __hip_atomic_store(dst, val, __ATOMIC_RELAXED, __HIP_MEMORY_SCOPE_AGENT);
    }
    asm volatile("s_waitcnt vmcnt(0)" ::: "memory");
    if (lane == 0) {
      unsigned* fp = (unsigned*)(mywf + (((size_t)t * 4 + m) * 96 + ws) * 2) + p;
      __hip_atomic_store(fp, (unsigned)(t + 1), __ATOMIC_RELAXED,
                         __HIP_MEMORY_SCOPE_AGENT);
    }

    // ---- deferred outputs (after flag; drain overlaps next wait) ----
    if constexpr (IS_L1) {
      out[((size_t)bb * T_ + t) * H_ + j] = h;  // ys
      if (t == T_ - 1) {
        out[BTH + BH + (size_t)bb * H_ + j] = h;
        out[BTH + 3 * BH + (size_t)bb * H_ + j] = c_reg;
      }
    } else {
      if (t == T_ - 1) {
        out[BTH + (size_t)bb * H_ + j] = h;
        out[BTH + 2 * BH + (size_t)bb * H_ + j] = c_reg;
      }
    }
  }
}

__launch_bounds__(512, 1)
__global__ void k_lstm(const f16_t* __restrict__ Xf,
                       const f16_t* __restrict__ Wih0f, const f16_t* __restrict__ Whh0f,
                       const f16_t* __restrict__ Wih1f, const f16_t* __restrict__ Whh1f,
                       const float* __restrict__ bsum0, const float* __restrict__ bsum1,
                       char* __restrict__ ring0c, char* __restrict__ ring1c,
                       u64* __restrict__ wf0, u64* __restrict__ wf1,
                       float* __restrict__ out) {
  extern __shared__ char smem[];
  const int wg = blockIdx.x;
  if (wg < 96)
    run_layer<32, false>(wg, Xf, Wih0f, Whh0f, bsum0, ring0c, ring1c,
                         wf0, wf1, out, smem);
  else
    run_layer<48, true>(wg - 96, Xf, Wih1f, Whh1f, bsum1, ring0c, ring1c,
                        wf0, wf1, out, smem);
}

// ---------------------------------------------------------------------------
extern "C" void kernel_launch(void* const* d_in, const int* in_sizes, int n_in,
                              void* d_out, int out_size, void* d_ws, size_t ws_size,
                              hipStream_t stream) {
  const float* x    = (const float*)d_in[0];
  const float* wih0 = (const float*)d_in[1];
  const float* whh0 = (const float*)d_in[2];
  const float* bih0 = (const float*)d_in[3];
  const float* bhh0 = (const float*)d_in[4];
  const float* wih1 = (const float*)d_in[5];
  const float* whh1 = (const float*)d_in[6];
  const float* bih1 = (const float*)d_in[7];
  const float* bhh1 = (const float*)d_in[8];
  float* out = (float*)d_out;

  char* base = (char*)d_ws;
  size_t off = 0;
  auto take = [&](size_t bytes) -> char* {
    char* r = base + off;
    off = (off + bytes + 255) & ~(size_t)255;
    return r;
  };
  f16_t* Wih0f = (f16_t*)take((size_t)G4H * I_ * 2);
  f16_t* Whh0f = (f16_t*)take((size_t)G4H * H_ * 2);
  f16_t* Wih1f = (f16_t*)take((size_t)G4H * H_ * 2);
  f16_t* Whh1f = (f16_t*)take((size_t)G4H * H_ * 2);
  f16_t* Xf    = (f16_t*)take((size_t)4 * T_ * 8 * 64 * 8 * 2);
  float* bsum0 = (float*)take((size_t)G4H * 4);
  float* bsum1 = (float*)take((size_t)G4H * 4);
  // rings (flag-gated; no zero needed) + per-wave flags (zeroed each call)
  char* ring0c = take(RING_BYTES);
  char* ring1c = take(RING_BYTES);
  char* fl = take(2 * WF_BYTES);
  u64* wf0 = (u64*)fl;
  u64* wf1 = wf0 + WF_U64S;

  hipFuncSetAttribute(reinterpret_cast<const void*>(k_lstm),
                      hipFuncAttributeMaxDynamicSharedMemorySize, SMEM_BYTES);

  k_packW<<<768, 256, 0, stream>>>(wih0, Wih0f, I_, 8, G4H * I_);
  k_packW<<<2048, 256, 0, stream>>>(whh0, Whh0f, H_, 24, G4H * H_);
  k_packW<<<2048, 256, 0, stream>>>(wih1, Wih1f, H_, 24, G4H * H_);
  k_packW<<<2048, 256, 0, stream>>>(whh1, Whh1f, H_, 24, G4H * H_);
  k_packX<<<4096, 256, 0, stream>>>(x, Xf);
  k_bias<<<12, 256, 0, stream>>>(bih0, bhh0, bsum0);
  k_bias<<<12, 256, 0, stream>>>(bih1, bhh1, bsum1);
  k_zero<<<1536, 256, 0, stream>>>((int4*)fl, (int)(2 * WF_BYTES / 16));

  k_lstm<<<192, 512, SMEM_BYTES, stream>>>(Xf, Wih0f, Whh0f, Wih1f, Whh1f,
                                           bsum0, bsum1, ring0c, ring1c,
                                           wf0, wf1, out);
}

// Round 14
// 2208.537 us; speedup vs baseline: 4.6996x; 4.6996x over previous
//
#include <hip/hip_runtime.h>
#include <math.h>

// ---------------------------------------------------------------------------
// 2-layer LSTM, B=64 T=512 I=256 H=768, fp32 in/out.
// Round 14: r13 (r10 + hierarchical flag aggregation) with the k_zero
// launch-coverage bug fixed (grid-stride loop; r13 left the super-flags
// un-zeroed -> stale tags on graph replay -> race).
//  - Producers: r10 (ring u64 quanta -> per-wave vmcnt(0) ack -> barrier ->
//    tid0 posts per-WG flag).
//  - 2 aggregator WGs (one per layer) tight-spin the 96 per-WG flags and
//    post ONE super-flag per (layer, step). Consumers spin on a single
//    wave-uniform line, then ONE one-shot data burst.
//  - Ring depth 16; L0 overwrite guard = single super1[t-16] check.
// Weights in LDS. fp16 MFMA 16x16x32, fragment-major operands.
// ---------------------------------------------------------------------------

#define B_   64
#define T_   512
#define I_   256
#define H_   768
#define G4H  3072

constexpr size_t BTH = (size_t)B_ * T_ * H_;   // 25165824
constexpr size_t BH  = (size_t)B_ * H_;        // 49152

using f16_t = _Float16;
using f16x8 = __attribute__((ext_vector_type(8))) _Float16;
using f32x4 = __attribute__((ext_vector_type(4))) float;
typedef unsigned long long u64;

#define MFMA(a, b, c) __builtin_amdgcn_mfma_f32_16x16x32_f16((a), (b), (c), 0, 0, 0)

// Ring: quantum u64 = 4 f16 units. addr = slot*98304 + ws*1024 + q*512 + b*8.
#define SLOT_STRIDE 98304    // 96*64*16 bytes
#define RING_SLOTS  16
#define RING_BYTES  (RING_SLOTS * SLOT_STRIDE)

// LDS partition (bytes): WL 0..98304 | pre 98304..132096 | bsL ..132224
#define SMEM_BYTES 132224

// ---------------------------------------------------------------------------
__global__ void k_packW(const float* __restrict__ src, f16_t* __restrict__ dst,
                        int K, int KC, int total) {
  int i = blockIdx.x * blockDim.x + threadIdx.x;
  int stride = gridDim.x * blockDim.x;
  for (; i < total; i += stride) {
    int e = i & 7;
    int lane = (i >> 3) & 63;
    int rest = i >> 9;          // ptile*KC + kc
    int kc = rest % KC;
    int ptile = rest / KC;
    int p = ptile * 16 + (lane & 15);
    int k = kc * 32 + (lane >> 4) * 8 + e;
    int r = (p & 3) * H_ + (p >> 2);
    dst[i] = (f16_t)src[(size_t)r * K + k];
  }
}

__global__ void k_packX(const float* __restrict__ x, f16_t* __restrict__ dst) {
  int i = blockIdx.x * blockDim.x + threadIdx.x;
  int stride = gridDim.x * blockDim.x;
  const int total = 4 * T_ * 8 * 64 * 8;  // 8,388,608
  for (; i < total; i += stride) {
    int e = i & 7;
    int lane = (i >> 3) & 63;
    int kc = (i >> 9) & 7;
    int t = (i >> 12) & 511;
    int mtile = i >> 21;
    int b = mtile * 16 + (lane & 15);
    int k = kc * 32 + (lane >> 4) * 8 + e;
    dst[i] = (f16_t)x[((size_t)b * T_ + t) * I_ + k];
  }
}

__global__ void k_bias(const float* __restrict__ bih, const float* __restrict__ bhh,
                       float* __restrict__ bsum) {
  int p = blockIdx.x * blockDim.x + threadIdx.x;
  if (p < G4H) {
    int r = (p & 3) * H_ + (p >> 2);
    bsum[p] = bih[r] + bhh[r];
  }
}

// Grid-stride zero (r13 bug: single-shot version silently under-covered).
__global__ void k_zero(int4* __restrict__ d, int n) {
  int stride = gridDim.x * blockDim.x;
  for (int i = blockIdx.x * blockDim.x + threadIdx.x; i < n; i += stride)
    d[i] = make_int4(0, 0, 0, 0);
}

__device__ __forceinline__ float sigf(float v) {
  return __builtin_amdgcn_rcpf(1.0f + __builtin_amdgcn_exp2f(v * -1.44269504f));
}
__device__ __forceinline__ float tanhf_fast(float v) {
  return 2.0f * __builtin_amdgcn_rcpf(1.0f + __builtin_amdgcn_exp2f(v * -2.88539008f)) - 1.0f;
}

__device__ __forceinline__ u64 ld_q(const u64* p) {
  return __hip_atomic_load(p, __ATOMIC_RELAXED, __HIP_MEMORY_SCOPE_AGENT);
}
__device__ __forceinline__ unsigned ld_flag(const int* p) {
  return (unsigned)__hip_atomic_load(p, __ATOMIC_RELAXED, __HIP_MEMORY_SCOPE_AGENT);
}

// Single-line super-flag spin (wave-uniform address -> 1 transaction/round).
__device__ __forceinline__ void wait_super(const int* p, unsigned tagv) {
  for (;;) {
    if (ld_flag(p) == tagv) return;
    __builtin_amdgcn_s_sleep(1);
  }
}

// One-shot burst (flag-guaranteed): per chunk i load q0,q1 for both mtiles,
// assemble f16x8 fragments, MFMA. (r10, unchanged.)
template <int KCW>
__device__ __forceinline__ void load_mfma(const char* sb, const int (&bA)[KCW],
                                          const f16_t* wl0, const f16_t* wl1,
                                          f32x4& a00, f32x4& a01, f32x4& a10,
                                          f32x4& a11) {
  u64 vA[KCW][2], vB[KCW][2];
#pragma unroll
  for (int i = 0; i < KCW; ++i) {
    const u64* p = (const u64*)(sb + bA[i]);
    vA[i][0] = ld_q(p);        // q0, mtile m0
    vA[i][1] = ld_q(p + 64);   // q1 (+512B)
    vB[i][0] = ld_q(p + 16);   // q0, mtile m0+1 (+128B)
    vB[i][1] = ld_q(p + 80);   // q1, mtile m0+1
  }
#pragma unroll
  for (int i = 0; i < KCW; ++i) {
    union { u64 q[2]; f16x8 f; } cA, cB;
    cA.q[0] = vA[i][0]; cA.q[1] = vA[i][1];
    cB.q[0] = vB[i][0]; cB.q[1] = vB[i][1];
    f16x8 w0 = *(const f16x8*)(wl0 + (size_t)i * 512);
    f16x8 w1 = *(const f16x8*)(wl1 + (size_t)i * 512);
    a00 = MFMA(cA.f, w0, a00);
    a01 = MFMA(cA.f, w1, a01);
    a10 = MFMA(cB.f, w0, a10);
    a11 = MFMA(cB.f, w1, a11);
  }
}

// ---------------------------------------------------------------------------
// Aggregator (one wave): for each t, detect all 96 per-WG flags == t+1, then
// post super[t] = t+1. Dedicated -> tight spin (no sleep) for fastest detect.
__device__ __forceinline__ void run_agg(const int* __restrict__ flags,
                                        int* __restrict__ sup) {
  if ((threadIdx.x >> 6) != 0) return;   // wave 0 only
  const int lane = threadIdx.x & 63;
  for (int t = 0; t < T_; ++t) {
    const int* f = flags + (size_t)t * 128 * 4;
    const unsigned want = (unsigned)(t + 1);
    for (;;) {
      unsigned v0 = ld_flag(f + lane * 4);
      unsigned v1 = (lane < 32) ? ld_flag(f + (64 + lane) * 4) : want;
      if (__all((v0 == want) & (v1 == want))) break;
    }
    asm volatile("s_waitcnt vmcnt(0)" ::: "memory");
    if (lane == 0)
      __hip_atomic_store(sup + (size_t)t * 4, (int)want, __ATOMIC_RELAXED,
                         __HIP_MEMORY_SCOPE_AGENT);
  }
}

// ---------------------------------------------------------------------------
// Persistent per-layer loop (r10 structure). 8 waves = mg(2) x kg(4);
// wave = 2x2 tile. L0: kg0 = x-GEMM (+ mg1: super1[t-16] ring guard);
// kg1-3 consume h0[t-1]. L1: kg0-1 consume h0[t], kg2-3 consume h1[t-1].
// Consumer release = super-flags (aggregated); producer per-WG flags feed
// only the aggregators.
template <int KCW, bool IS_L1>
__device__ __forceinline__ void run_layer(
    int ws, const f16_t* __restrict__ Xf, const f16_t* __restrict__ Wihf,
    const f16_t* __restrict__ Whhf, const float* __restrict__ bsum,
    char* __restrict__ ring0c, char* __restrict__ ring1c,
    int* __restrict__ flag0, int* __restrict__ flag1,
    int* __restrict__ sup0, int* __restrict__ sup1,
    float* __restrict__ out, char* smem) {
  f16_t* WL = (f16_t*)smem;                              // [4 kg][2 p][KCW][512]
  float (*pre)[64][33] = (float (*)[64][33])(smem + 98304);
  float* bsL = (float*)(smem + 132096);                  // [32]

  const int tid = threadIdx.x;
  const int wave = tid >> 6, lane = tid & 63;
  const int kg = wave & 3, mg = wave >> 2;
  const int laneo = lane * 8;
  const int pt0 = ws * 2, m0 = mg * 2;
  const int l15 = lane & 15, l4 = lane >> 4;

  if (tid < 32) bsL[tid] = bsum[ws * 32 + tid];

  // ---- stage W into LDS (mg==0 waves) ----
  if (mg == 0) {
    const f16_t* src;
    int KC, kc0;
    if constexpr (!IS_L1) {
      if (kg == 0) { src = Wihf; KC = 8;  kc0 = 0; }
      else         { src = Whhf; KC = 24; kc0 = (kg - 1) * 8; }
    } else {
      if (kg < 2)  { src = Wihf; KC = 24; kc0 = kg * 12; }
      else         { src = Whhf; KC = 24; kc0 = (kg - 2) * 12; }
    }
#pragma unroll
    for (int p = 0; p < 2; ++p)
#pragma unroll
      for (int i = 0; i < KCW; ++i)
        *(uint4*)(WL + ((size_t)((kg * 2 + p) * KCW + i)) * 512 + laneo) =
            *(const uint4*)(src + ((size_t)(pt0 + p) * KC + kc0 + i) * 512 + laneo);
  }

  // Consumer chunk start (32-unit chunks of the source h vector).
  int kcs = 0;
  if constexpr (!IS_L1) kcs = (kg - 1) * 8;      // valid for kg>=1
  else                  kcs = (kg < 2) ? kg * 12 : (kg - 2) * 12;

  // Byte offset of chunk i's base quantum: producer ws'=(kcs+i)*4+l4,
  // batch row = m0*16+l15.
  int bA[KCW];
#pragma unroll
  for (int i = 0; i < KCW; ++i)
    bA[i] = ((kcs + i) * 4 + l4) * 1024 + (m0 * 16 + l15) * 8;

  float c_reg = 0.f;
  const int u = tid & 7, b = tid >> 3;
  const int j = ws * 8 + u;
  char* myringc = IS_L1 ? ring1c : ring0c;
  int* myflag = IS_L1 ? flag1 : flag0;
  const f16_t* wl0 = WL + (size_t)(kg * 2) * KCW * 512 + laneo;
  const f16_t* wl1 = wl0 + (size_t)KCW * 512;

  __syncthreads();

  for (int t = 0; t < T_; ++t) {
    f32x4 a00 = {0.f, 0.f, 0.f, 0.f};
    f32x4 a01 = {0.f, 0.f, 0.f, 0.f};
    f32x4 a10 = {0.f, 0.f, 0.f, 0.f};
    f32x4 a11 = {0.f, 0.f, 0.f, 0.f};

    if constexpr (!IS_L1) {
      if (kg == 0) {
        // ring guard: before publishing h0[t] over h0[t-16]'s slot, all L1
        // WGs must be past step t-16 (single super-flag check, off-path).
        if (mg == 1 && t >= RING_SLOTS)
          wait_super(sup1 + (size_t)(t - RING_SLOTS) * 4,
                     (unsigned)(t - RING_SLOTS + 1));
        // x_t @ Wih0^T (no recurrence dependency)
        const f16_t* A0 = Xf + ((size_t)m0 * T_ + t) * 4096 + laneo;
        const f16_t* A1 = A0 + (size_t)T_ * 4096;
#pragma unroll
        for (int i = 0; i < KCW; ++i) {
          f16x8 x0 = *(const f16x8*)(A0 + (size_t)i * 512);
          f16x8 x1 = *(const f16x8*)(A1 + (size_t)i * 512);
          f16x8 w0 = *(const f16x8*)(wl0 + (size_t)i * 512);
          f16x8 w1 = *(const f16x8*)(wl1 + (size_t)i * 512);
          a00 = MFMA(x0, w0, a00);
          a01 = MFMA(x0, w1, a01);
          a10 = MFMA(x1, w0, a10);
          a11 = MFMA(x1, w1, a11);
        }
      } else if (t >= 1) {
        wait_super(sup0 + (size_t)(t - 1) * 4, (unsigned)t);
        const char* sb = ring0c + (size_t)((t - 1) & (RING_SLOTS - 1)) * SLOT_STRIDE;
        load_mfma<KCW>(sb, bA, wl0, wl1, a00, a01, a10, a11);
      }
    } else {
      const int srcstep = (kg < 2) ? t : t - 1;
      if (srcstep >= 0) {
        const unsigned tg = (unsigned)(srcstep + 1);
        wait_super(((kg < 2) ? sup0 : sup1) + (size_t)srcstep * 4, tg);
        const char* sb = ((kg < 2) ? ring0c : ring1c) +
                         (size_t)(srcstep & (RING_SLOTS - 1)) * SLOT_STRIDE;
        load_mfma<KCW>(sb, bA, wl0, wl1, a00, a01, a10, a11);
      }
    }

    // ---- partial-sum exchange (C layout: col=lane&15, row=l4*4+r) ----
#pragma unroll
    for (int r = 0; r < 4; ++r) {
      pre[kg][m0 * 16 + l4 * 4 + r][l15]           = a00[r];
      pre[kg][m0 * 16 + l4 * 4 + r][16 + l15]      = a01[r];
      pre[kg][m0 * 16 + 16 + l4 * 4 + r][l15]      = a10[r];
      pre[kg][m0 * 16 + 16 + l4 * 4 + r][16 + l15] = a11[r];
    }
    __syncthreads();

    // ---- gate phase: thread = (u = tid&7, b = tid>>3) ----
    float h;
    {
      float g0 = pre[0][b][4 * u + 0] + pre[1][b][4 * u + 0] + pre[2][b][4 * u + 0] + pre[3][b][4 * u + 0] + bsL[4 * u + 0];
      float g1 = pre[0][b][4 * u + 1] + pre[1][b][4 * u + 1] + pre[2][b][4 * u + 1] + pre[3][b][4 * u + 1] + bsL[4 * u + 1];
      float g2 = pre[0][b][4 * u + 2] + pre[1][b][4 * u + 2] + pre[2][b][4 * u + 2] + pre[3][b][4 * u + 2] + bsL[4 * u + 2];
      float g3 = pre[0][b][4 * u + 3] + pre[1][b][4 * u + 3] + pre[2][b][4 * u + 3] + pre[3][b][4 * u + 3] + bsL[4 * u + 3];
      float ig = sigf(g0), fg = sigf(g1), gg = tanhf_fast(g2), og = sigf(g3);
      c_reg = fg * c_reg + ig * gg;
      h = og * tanhf_fast(c_reg);

      // ring publish: gather 4 units via shfl, u%4==0 stores one u64 quantum.
      unsigned hb = (unsigned)__builtin_bit_cast(unsigned short, (f16_t)h);
      unsigned n1 = (unsigned)__shfl((int)hb, lane + 1);
      unsigned n2 = (unsigned)__shfl((int)hb, lane + 2);
      unsigned n3 = (unsigned)__shfl((int)hb, lane + 3);
      if ((u & 3) == 0) {
        u64 val = (u64)(hb | (n1 << 16)) | ((u64)(n2 | (n3 << 16)) << 32);
        u64* dst = (u64*)(myringc +
                          (size_t)(t & (RING_SLOTS - 1)) * SLOT_STRIDE +
                          (size_t)ws * 1024 + (u >> 2) * 512 + (size_t)b * 8);
        __hip_atomic_store(dst, val, __ATOMIC_RELAXED, __HIP_MEMORY_SCOPE_AGENT);
      }
    }
    // per-wave ack of own ring stores (parallel across waves), then publish.
    asm volatile("s_waitcnt vmcnt(0)" ::: "memory");
    __syncthreads();
    if (tid == 0)
      __hip_atomic_store(myflag + ((size_t)t * 128 + ws) * 4, t + 1,
                         __ATOMIC_RELAXED, __HIP_MEMORY_SCOPE_AGENT);

    // ---- deferred outputs (off critical path) ----
    if constexpr (IS_L1) {
      out[((size_t)b * T_ + t) * H_ + j] = h;  // ys
      if (t == T_ - 1) {
        out[BTH + BH + (size_t)b * H_ + j] = h;
        out[BTH + 3 * BH + (size_t)b * H_ + j] = c_reg;
      }
    } else {
      if (t == T_ - 1) {
        out[BTH + (size_t)b * H_ + j] = h;
        out[BTH + 2 * BH + (size_t)b * H_ + j] = c_reg;
      }
    }
  }
}

__launch_bounds__(512, 1)
__global__ void k_lstm(const f16_t* __restrict__ Xf,
                       const f16_t* __restrict__ Wih0f, const f16_t* __restrict__ Whh0f,
                       const f16_t* __restrict__ Wih1f, const f16_t* __restrict__ Whh1f,
                       const float* __restrict__ bsum0, const float* __restrict__ bsum1,
                       char* __restrict__ ring0c, char* __restrict__ ring1c,
                       int* __restrict__ flag0, int* __restrict__ flag1,
                       int* __restrict__ sup0, int* __restrict__ sup1,
                       float* __restrict__ out) {
  extern __shared__ char smem[];
  const int wg = blockIdx.x;
  if (wg < 96)
    run_layer<8, false>(wg, Xf, Wih0f, Whh0f, bsum0, ring0c, ring1c,
                        flag0, flag1, sup0, sup1, out, smem);
  else if (wg < 192)
    run_layer<12, true>(wg - 96, Xf, Wih1f, Whh1f, bsum1, ring0c, ring1c,
                        flag0, flag1, sup0, sup1, out, smem);
  else if (wg == 192)
    run_agg(flag0, sup0);
  else
    run_agg(flag1, sup1);
}

// ---------------------------------------------------------------------------
extern "C" void kernel_launch(void* const* d_in, const int* in_sizes, int n_in,
                              void* d_out, int out_size, void* d_ws, size_t ws_size,
                              hipStream_t stream) {
  const float* x    = (const float*)d_in[0];
  const float* wih0 = (const float*)d_in[1];
  const float* whh0 = (const float*)d_in[2];
  const float* bih0 = (const float*)d_in[3];
  const float* bhh0 = (const float*)d_in[4];
  const float* wih1 = (const float*)d_in[5];
  const float* whh1 = (const float*)d_in[6];
  const float* bih1 = (const float*)d_in[7];
  const float* bhh1 = (const float*)d_in[8];
  float* out = (float*)d_out;

  char* base = (char*)d_ws;
  size_t off = 0;
  auto take = [&](size_t bytes) -> char* {
    char* r = base + off;
    off = (off + bytes + 255) & ~(size_t)255;
    return r;
  };
  f16_t* Wih0f = (f16_t*)take((size_t)G4H * I_ * 2);
  f16_t* Whh0f = (f16_t*)take((size_t)G4H * H_ * 2);
  f16_t* Wih1f = (f16_t*)take((size_t)G4H * H_ * 2);
  f16_t* Whh1f = (f16_t*)take((size_t)G4H * H_ * 2);
  f16_t* Xf    = (f16_t*)take((size_t)4 * T_ * 8 * 64 * 8 * 2);
  float* bsum0 = (float*)take((size_t)G4H * 4);
  float* bsum1 = (float*)take((size_t)G4H * 4);
  // rings (flag-gated; no zero needed) + per-WG flags + super-flags (zeroed)
  char* ring0c = take(RING_BYTES);
  char* ring1c = take(RING_BYTES);
  const size_t flagBytes = (size_t)T_ * 128 * 16;        // 1 MB each
  const size_t supBytes  = (size_t)T_ * 16;              // 8 KB each
  char* fl = take(2 * flagBytes + 2 * supBytes);
  int* flag0 = (int*)fl;
  int* flag1 = flag0 + (size_t)T_ * 128 * 4;
  int* sup0  = flag1 + (size_t)T_ * 128 * 4;
  int* sup1  = sup0 + (size_t)T_ * 4;
  const size_t zeroBytes = 2 * flagBytes + 2 * supBytes;

  hipFuncSetAttribute(reinterpret_cast<const void*>(k_lstm),
                      hipFuncAttributeMaxDynamicSharedMemorySize, SMEM_BYTES);

  k_packW<<<768, 256, 0, stream>>>(wih0, Wih0f, I_, 8, G4H * I_);
  k_packW<<<2048, 256, 0, stream>>>(whh0, Whh0f, H_, 24, G4H * H_);
  k_packW<<<2048, 256, 0, stream>>>(wih1, Wih1f, H_, 24, G4H * H_);
  k_packW<<<2048, 256, 0, stream>>>(whh1, Whh1f, H_, 24, G4H * H_);
  k_packX<<<4096, 256, 0, stream>>>(x, Xf);
  k_bias<<<12, 256, 0, stream>>>(bih0, bhh0, bsum0);
  k_bias<<<12, 256, 0, stream>>>(bih1, bhh1, bsum1);
  k_zero<<<520, 256, 0, stream>>>((int4*)fl, (int)(zeroBytes / 16));

  k_lstm<<<194, 512, SMEM_BYTES, stream>>>(Xf, Wih0f, Whh0f, Wih1f, Whh1f,
                                           bsum0, bsum1, ring0c, ring1c,
                                           flag0, flag1, sup0, sup1, out);
}